// Round 8
// baseline (197.518 us; speedup 1.0000x reference)
//
#include <hip/hip_runtime.h>
#include <math.h>

// B=32, HID=4096, NH=32, NKV=8, HS=128, BS=16, MAXS=2048, groups=4

// ---------------------------------------------------------------------------
// Split-K f32 GEMM v1 (known-good). out[b][n] += x[b][:] . w[n][:].
// BM=32, BN=256, BK=32. 256 threads, 32 accumulators/thread.
// ---------------------------------------------------------------------------
__device__ __forceinline__ void gemm_body(
    const float* __restrict__ x, const float* __restrict__ w,
    float* __restrict__ dst, int dstride, int kbase, int kcnt)
{
    __shared__ float xs[32][36];
    __shared__ float wsm[32][257];   // [k][n]
    int t = threadIdx.x;
    float acc[4][8];
#pragma unroll
    for (int i = 0; i < 4; ++i)
#pragma unroll
        for (int j = 0; j < 8; ++j) acc[i][j] = 0.f;

    int nsub = t & 31, bsub = t >> 5;

    for (int kt = 0; kt < kcnt; kt += 32) {
        int k0 = kbase + kt;
        {
            int b = t >> 3, k4 = (t & 7) << 2;
            float4 xv = *(const float4*)(x + (size_t)b * 4096 + k0 + k4);
            *(float4*)&xs[b][k4] = xv;
        }
        {
            int k4 = (t & 7) << 2;
            int nl0 = t >> 3;
#pragma unroll
            for (int i = 0; i < 8; ++i) {
                int nl = nl0 + (i << 5);
                float4 wv = *(const float4*)(w + (size_t)nl * 4096 + k0 + k4);
                wsm[k4 + 0][nl] = wv.x;
                wsm[k4 + 1][nl] = wv.y;
                wsm[k4 + 2][nl] = wv.z;
                wsm[k4 + 3][nl] = wv.w;
            }
        }
        __syncthreads();
#pragma unroll
        for (int k = 0; k < 32; ++k) {
            float xv[4], wv[8];
#pragma unroll
            for (int j = 0; j < 4; ++j) xv[j] = xs[bsub * 4 + j][k];
#pragma unroll
            for (int j = 0; j < 8; ++j) wv[j] = wsm[k][nsub + (j << 5)];
#pragma unroll
            for (int jb = 0; jb < 4; ++jb)
#pragma unroll
                for (int jn = 0; jn < 8; ++jn)
                    acc[jb][jn] = fmaf(xv[jb], wv[jn], acc[jb][jn]);
        }
        __syncthreads();
    }
#pragma unroll
    for (int jb = 0; jb < 4; ++jb) {
        int b = bsub * 4 + jb;
#pragma unroll
        for (int jn = 0; jn < 8; ++jn)
            atomicAdd(dst + (size_t)b * dstride + nsub + (jn << 5), acc[jb][jn]);
    }
}

// grid = 24 tiles * 16 splits
__global__ __launch_bounds__(256) void qkv_gemm(
    const float* __restrict__ x, const float* __restrict__ wq,
    const float* __restrict__ wk, const float* __restrict__ wv,
    float* __restrict__ qb, float* __restrict__ knb, float* __restrict__ vnb)
{
    int split = blockIdx.x & 15;
    int tile  = blockIdx.x >> 4;
    const float* w; float* dst; int dstride;
    if (tile < 16)      { w = wq + (size_t)tile * 256 * 4096;        dst = qb  + tile * 256;        dstride = 4096; }
    else if (tile < 20) { w = wk + (size_t)(tile - 16) * 256 * 4096; dst = knb + (tile - 16) * 256; dstride = 1024; }
    else                { w = wv + (size_t)(tile - 20) * 256 * 4096; dst = vnb + (tile - 20) * 256; dstride = 1024; }
    gemm_body(x, w, dst, dstride, split * 256, 256);
}

// grid = 16 tiles * 16 splits
__global__ __launch_bounds__(256) void wo_gemm(
    const float* __restrict__ attn, const float* __restrict__ wo,
    float* __restrict__ out)
{
    int split = blockIdx.x & 15;
    int tile  = blockIdx.x >> 4;
    gemm_body(attn, wo + (size_t)tile * 256 * 4096, out + tile * 256, 4096, split * 256, 256);
}

// ---------------------------------------------------------------------------
// RoPE in-place on q (32 heads) and k_new (8 heads). grid = 32*40, block = 64.
// ---------------------------------------------------------------------------
__global__ void rope_kernel(float* __restrict__ qb, float* __restrict__ knb,
                            const int* __restrict__ lens)
{
    int bid = blockIdx.x;
    int b = bid / 40, r = bid % 40;
    float* row = (r < 32) ? (qb + (size_t)b * 4096 + r * 128)
                          : (knb + (size_t)b * 1024 + (r - 32) * 128);
    int d = threadIdx.x;
    float pos = (float)(lens[b] - 1);
    float inv = exp2f(-(float)d * 0.207620505930460f);  // 10000^(-d/64)
    float fr = pos * inv;
    float s, c;
    sincosf(fr, &s, &c);
    float x1 = row[d], x2 = row[d + 64];
    row[d]      = x1 * c - x2 * s;
    row[d + 64] = x2 * c + x1 * s;
}

// ---------------------------------------------------------------------------
// Flash-decode attention. grid = 32*8*8 chunks of 256 positions, block = 256,
// TILE=64 rows, V double-buffered (vA/vB named regs), K prefetched to regs.
// NEW vs R7: in-loop barriers are RAW s_barrier + lgkmcnt(0) only (T3/T4).
// __syncthreads() forces s_waitcnt vmcnt(0) before s_barrier, draining every
// prefetch mid-tile (why R2/R7 pipelines were null). Raw barrier keeps V/K
// loads in flight across barriers; their only waits are compiler-inserted
// COUNTED vmcnt data-dep waits at the consumption points.
// launch_bounds(256,1): NEVER cap VGPRs below live-set (R5: cap -> spill).
// ---------------------------------------------------------------------------
#define BARRIER_NODRAIN() { \
    asm volatile("s_waitcnt lgkmcnt(0)" ::: "memory"); \
    __builtin_amdgcn_s_barrier(); \
    __builtin_amdgcn_sched_barrier(0); }

#define LOADK(tile_) { \
    int sl = ss[((tile_) << 6) + pr_row]; \
    const float* ksrc = (sl < 0) ? knew : (kc + (size_t)sl * 1024 + hoff); \
    ksrc += pr_q * 32; \
    k0 = *(const float4*)(ksrc);      k1 = *(const float4*)(ksrc + 4); \
    k2 = *(const float4*)(ksrc + 8);  k3 = *(const float4*)(ksrc + 12); \
    k4 = *(const float4*)(ksrc + 16); k5 = *(const float4*)(ksrc + 20); \
    k6 = *(const float4*)(ksrc + 24); k7 = *(const float4*)(ksrc + 28); }

#define COMMITK() { \
    *(float4*)&ks[pr_row][((q8 + 0) ^ r7) << 2] = k0; \
    *(float4*)&ks[pr_row][((q8 + 1) ^ r7) << 2] = k1; \
    *(float4*)&ks[pr_row][((q8 + 2) ^ r7) << 2] = k2; \
    *(float4*)&ks[pr_row][((q8 + 3) ^ r7) << 2] = k3; \
    *(float4*)&ks[pr_row][((q8 + 4) ^ r7) << 2] = k4; \
    *(float4*)&ks[pr_row][((q8 + 5) ^ r7) << 2] = k5; \
    *(float4*)&ks[pr_row][((q8 + 6) ^ r7) << 2] = k6; \
    *(float4*)&ks[pr_row][((q8 + 7) ^ r7) << 2] = k7; }

#define LOADV1(PRE, i_, ib_) { \
    int sl = ss[(ib_) + i_]; \
    const float* vsrc = (sl < 0) ? vnew : (vc + (size_t)sl * 1024 + hoff); \
    PRE##i_ = *(const float2*)(vsrc + d0); }

#define LOADVSET(PRE, tile_) { \
    int ib_ = ((tile_) << 6) + rp0; \
    LOADV1(PRE, 0, ib_)  LOADV1(PRE, 1, ib_)  LOADV1(PRE, 2, ib_)  LOADV1(PRE, 3, ib_) \
    LOADV1(PRE, 4, ib_)  LOADV1(PRE, 5, ib_)  LOADV1(PRE, 6, ib_)  LOADV1(PRE, 7, ib_) \
    LOADV1(PRE, 8, ib_)  LOADV1(PRE, 9, ib_)  LOADV1(PRE, 10, ib_) LOADV1(PRE, 11, ib_) \
    LOADV1(PRE, 12, ib_) LOADV1(PRE, 13, ib_) LOADV1(PRE, 14, ib_) LOADV1(PRE, 15, ib_) }

#define PVQ(i_, A0, A1, A2, A3) { \
    float4 w0 = *(const float4*)&ps[0][rp0 + i_]; \
    float4 w1 = *(const float4*)&ps[1][rp0 + i_]; \
    float4 w2 = *(const float4*)&ps[2][rp0 + i_]; \
    float4 w3 = *(const float4*)&ps[3][rp0 + i_]; \
    o00 = fmaf(w0.x, A0.x, o00); o01 = fmaf(w0.x, A0.y, o01); \
    o00 = fmaf(w0.y, A1.x, o00); o01 = fmaf(w0.y, A1.y, o01); \
    o00 = fmaf(w0.z, A2.x, o00); o01 = fmaf(w0.z, A2.y, o01); \
    o00 = fmaf(w0.w, A3.x, o00); o01 = fmaf(w0.w, A3.y, o01); \
    o10 = fmaf(w1.x, A0.x, o10); o11 = fmaf(w1.x, A0.y, o11); \
    o10 = fmaf(w1.y, A1.x, o10); o11 = fmaf(w1.y, A1.y, o11); \
    o10 = fmaf(w1.z, A2.x, o10); o11 = fmaf(w1.z, A2.y, o11); \
    o10 = fmaf(w1.w, A3.x, o10); o11 = fmaf(w1.w, A3.y, o11); \
    o20 = fmaf(w2.x, A0.x, o20); o21 = fmaf(w2.x, A0.y, o21); \
    o20 = fmaf(w2.y, A1.x, o20); o21 = fmaf(w2.y, A1.y, o21); \
    o20 = fmaf(w2.z, A2.x, o20); o21 = fmaf(w2.z, A2.y, o21); \
    o20 = fmaf(w2.w, A3.x, o20); o21 = fmaf(w2.w, A3.y, o21); \
    o30 = fmaf(w3.x, A0.x, o30); o31 = fmaf(w3.x, A0.y, o31); \
    o30 = fmaf(w3.y, A1.x, o30); o31 = fmaf(w3.y, A1.y, o31); \
    o30 = fmaf(w3.z, A2.x, o30); o31 = fmaf(w3.z, A2.y, o31); \
    o30 = fmaf(w3.w, A3.x, o30); o31 = fmaf(w3.w, A3.y, o31); }

#define PVALL(PRE) { \
    float c0 = corrs[0], c1 = corrs[1], c2 = corrs[2], c3 = corrs[3]; \
    o00 *= c0; o01 *= c0; o10 *= c1; o11 *= c1; \
    o20 *= c2; o21 *= c2; o30 *= c3; o31 *= c3; \
    PVQ(0,  PRE##0,  PRE##1,  PRE##2,  PRE##3) \
    PVQ(4,  PRE##4,  PRE##5,  PRE##6,  PRE##7) \
    PVQ(8,  PRE##8,  PRE##9,  PRE##10, PRE##11) \
    PVQ(12, PRE##12, PRE##13, PRE##14, PRE##15) }

#define SCORES(TT) { \
    int tlen = min(pend - ((TT) << 6), 64); \
    float ax = 0.f, ay = 0.f, az = 0.f, aw = 0.f; \
    _Pragma("unroll") \
    for (int cc = 0; cc < 32; ++cc) { \
        float4 kv = *(float4*)&ks[lane][(cc ^ xm) << 2]; \
        float4 qv = *(const float4*)&qs[wave][cc << 2]; \
        ax = fmaf(kv.x, qv.x, ax); \
        ay = fmaf(kv.y, qv.y, ay); \
        az = fmaf(kv.z, qv.z, az); \
        aw = fmaf(kv.w, qv.w, aw); \
    } \
    float s = (lane < tlen) ? (ax + ay + az + aw) * scale : -INFINITY; \
    float smax = s; \
    _Pragma("unroll") \
    for (int off = 32; off; off >>= 1) smax = fmaxf(smax, __shfl_xor(smax, off, 64)); \
    float mnew = fmaxf(m, smax); \
    float corr = __expf(m - mnew); \
    float pexp = (lane < tlen) ? __expf(s - mnew) : 0.f; \
    float psum = pexp; \
    _Pragma("unroll") \
    for (int off = 32; off; off >>= 1) psum += __shfl_xor(psum, off, 64); \
    lsum = lsum * corr + psum; \
    m = mnew; \
    ps[wave][lane] = pexp; \
    if (lane == 0) corrs[wave] = corr; }

__global__ __launch_bounds__(256, 1) void attn_kernel(
    const float* __restrict__ kc, const float* __restrict__ vc,
    const float* __restrict__ qb, const float* __restrict__ knb,
    const float* __restrict__ vnb,
    const int* __restrict__ btab, const int* __restrict__ lens,
    float* __restrict__ part)
{
    int bid = blockIdx.x;
    int c = bid & 7, h = (bid >> 3) & 7, b = bid >> 6;
    int len = lens[b];
    int p0 = c << 8;
    if (p0 >= len) return;
    int pend = min(len - p0, 256);
    int nt = (pend + 63) >> 6;
    int last = len - 1;

    __shared__ float ks[64][128];   // 32 KB, f4-col XOR-swizzled
    __shared__ float qs[4][128];
    __shared__ float ps[4][64];
    __shared__ int   ss[256];       // slot table; -1 => new k/v row
    __shared__ float corrs[4];

    int t = threadIdx.x;
    int wave = t >> 6, lane = t & 63;
    int hoff = h * 128;

    {   // slot table for the whole chunk
        int p = p0 + t;
        ss[t] = (p == last) ? -1 : (btab[b * 128 + (p >> 4)] * 16 + (p & 15));
    }
    if (t < 128) {
        int g = t >> 5, d4 = (t & 31) << 2;
        *(float4*)&qs[g][d4] =
            *(const float4*)(qb + (size_t)b * 4096 + (size_t)(h * 4 + g) * 128 + d4);
    }
    __syncthreads();

    int pr_row = t >> 2;          // 0..63
    int pr_q   = t & 3;           // 128B quarter of the row
    int q8 = pr_q << 3;
    int r7 = pr_row & 7;
    const float* knew = knb + ((size_t)b * 8 + h) * 128;
    const float* vnew = vnb + ((size_t)b * 8 + h) * 128;

    const float scale = 0.08838834764831845f;
    int xm = lane & 7;
    int d0 = lane << 1;
    int rp0 = wave << 4;

    float4 k0, k1, k2, k3, k4, k5, k6, k7;
    float2 vA0, vA1, vA2, vA3, vA4, vA5, vA6, vA7;
    float2 vA8, vA9, vA10, vA11, vA12, vA13, vA14, vA15;
    float2 vB0, vB1, vB2, vB3, vB4, vB5, vB6, vB7;
    float2 vB8, vB9, vB10, vB11, vB12, vB13, vB14, vB15;

    LOADK(0)
    COMMITK()
    LOADVSET(vA, 0)               // V tile 0 in flight across the prologue
    __syncthreads();

    float m = -INFINITY, lsum = 0.f;
    float o00 = 0.f, o01 = 0.f, o10 = 0.f, o11 = 0.f;
    float o20 = 0.f, o21 = 0.f, o30 = 0.f, o31 = 0.f;

    for (int tt = 0; tt < nt; tt += 2) {
        // ===== even tile tt: consume vA, prefetch vB(t+1), K(t+1) =====
        if (tt + 1 < nt) { LOADVSET(vB, tt + 1) LOADK(tt + 1) }
        SCORES(tt)
        BARRIER_NODRAIN()         // C: ps/corrs visible; ks(t) reads done
        PVALL(vA)
        if (tt + 1 < nt) COMMITK()
        BARRIER_NODRAIN()         // F: ks(t+1) ready; ps consumed
        if (tt + 1 >= nt) break;
        // ===== odd tile tt+1: consume vB, prefetch vA(t+2), K(t+2) =====
        if (tt + 2 < nt) { LOADVSET(vA, tt + 2) LOADK(tt + 2) }
        SCORES(tt + 1)
        BARRIER_NODRAIN()         // C
        PVALL(vB)
        if (tt + 2 < nt) COMMITK()
        BARRIER_NODRAIN()         // F
    }

    // epilogue: cross-wave O reduction (overlay scratch on ks)
    float* oacc = (float*)ks;   // [wave][g][128]
    oacc[(wave * 4 + 0) * 128 + d0]     = o00;
    oacc[(wave * 4 + 0) * 128 + d0 + 1] = o01;
    oacc[(wave * 4 + 1) * 128 + d0]     = o10;
    oacc[(wave * 4 + 1) * 128 + d0 + 1] = o11;
    oacc[(wave * 4 + 2) * 128 + d0]     = o20;
    oacc[(wave * 4 + 2) * 128 + d0 + 1] = o21;
    oacc[(wave * 4 + 3) * 128 + d0]     = o30;
    oacc[(wave * 4 + 3) * 128 + d0 + 1] = o31;
    float* pgbase = part + (size_t)(((b * 8 + h) * 8 + c) * 4) * 130;
    if (lane == 0) { pgbase[wave * 130] = m; pgbase[wave * 130 + 1] = lsum; }
    __syncthreads();
    for (int e = t; e < 512; e += 256) {
        int g = e >> 7, d = e & 127;
        float v = oacc[(0 + g) * 128 + d] + oacc[(4 + g) * 128 + d]
                + oacc[(8 + g) * 128 + d] + oacc[(12 + g) * 128 + d];
        pgbase[g * 130 + 2 + d] = v;
    }
}

// grid = 256 (b*8+h), block = 256 (4 groups x 64 lanes)
__global__ __launch_bounds__(256) void combine_kernel(
    const float* __restrict__ part, const int* __restrict__ lens,
    float* __restrict__ attn)
{
    int b = blockIdx.x >> 3, h = blockIdx.x & 7;
    int t = threadIdx.x;
    int g = t >> 6, lane = t & 63;
    int len = lens[b];
    int nch = (len + 255) >> 8;
    size_t base = ((size_t)(b * 8 + h) * 32 + g) * 130;
    float M = -INFINITY;
    for (int cc = 0; cc < nch; ++cc)
        M = fmaxf(M, part[base + (size_t)cc * 520]);
    float denom = 0.f, a0 = 0.f, a1 = 0.f;
    for (int cc = 0; cc < nch; ++cc) {
        const float* pg = part + base + (size_t)cc * 520;
        float w = __expf(pg[0] - M);
        denom += w * pg[1];
        a0 += w * pg[2 + (lane << 1)];
        a1 += w * pg[3 + (lane << 1)];
    }
    float inv = 1.f / denom;
    float* dst = attn + (size_t)b * 4096 + (size_t)(h * 4 + g) * 128 + (lane << 1);
    dst[0] = a0 * inv;
    dst[1] = a1 * inv;
}

// ---------------------------------------------------------------------------
// Workspace (floats): qb[32][4096] @0, knb[32*1024] @131072, vnb @163840,
// attn[32][4096] @196608, part[32*8*8*4*130] @327680  (~5.6 MB)
// ---------------------------------------------------------------------------
extern "C" void kernel_launch(void* const* d_in, const int* in_sizes, int n_in,
                              void* d_out, int out_size, void* d_ws, size_t ws_size,
                              hipStream_t stream)
{
    const float* x   = (const float*)d_in[0];
    const float* wq  = (const float*)d_in[1];
    const float* wk  = (const float*)d_in[2];
    const float* wv  = (const float*)d_in[3];
    const float* wo  = (const float*)d_in[4];
    const float* kc  = (const float*)d_in[5];
    const float* vc  = (const float*)d_in[6];
    const int* btab  = (const int*)d_in[8];
    const int* lens  = (const int*)d_in[10];

    float* qb   = (float*)d_ws;
    float* knb  = qb  + 32 * 4096;
    float* vnb  = knb + 32 * 1024;
    float* attn = vnb + 32 * 1024;
    float* part = attn + 32 * 4096;
    float* outp = (float*)d_out;

    hipMemsetAsync(d_ws, 0, (size_t)(32 * 4096 + 2 * 32 * 1024) * sizeof(float), stream);
    hipMemsetAsync(d_out, 0, (size_t)32 * 4096 * sizeof(float), stream);

    qkv_gemm<<<24 * 16, 256, 0, stream>>>(x, wq, wk, wv, qb, knb, vnb);
    rope_kernel<<<32 * 40, 64, 0, stream>>>(qb, knb, lens);
    attn_kernel<<<2048, 256, 0, stream>>>(kc, vc, qb, knb, vnb, btab, lens, part);
    combine_kernel<<<256, 256, 0, stream>>>(part, lens, attn);
    wo_gemm<<<16 * 16, 256, 0, stream>>>(attn, wo, outp);
}

// Round 9
// 178.832 us; speedup vs baseline: 1.1045x; 1.1045x over previous
//
#include <hip/hip_runtime.h>
#include <math.h>

// B=32, HID=4096, NH=32, NKV=8, HS=128, BS=16, MAXS=2048, groups=4

// ---------------------------------------------------------------------------
// Split-K f32 GEMM v1 (known-good). out[b][n] += x[b][:] . w[n][:].
// BM=32, BN=256, BK=32. 256 threads, 32 accumulators/thread.
// ---------------------------------------------------------------------------
__device__ __forceinline__ void gemm_body(
    const float* __restrict__ x, const float* __restrict__ w,
    float* __restrict__ dst, int dstride, int kbase, int kcnt)
{
    __shared__ float xs[32][36];
    __shared__ float wsm[32][257];   // [k][n]
    int t = threadIdx.x;
    float acc[4][8];
#pragma unroll
    for (int i = 0; i < 4; ++i)
#pragma unroll
        for (int j = 0; j < 8; ++j) acc[i][j] = 0.f;

    int nsub = t & 31, bsub = t >> 5;

    for (int kt = 0; kt < kcnt; kt += 32) {
        int k0 = kbase + kt;
        {
            int b = t >> 3, k4 = (t & 7) << 2;
            float4 xv = *(const float4*)(x + (size_t)b * 4096 + k0 + k4);
            *(float4*)&xs[b][k4] = xv;
        }
        {
            int k4 = (t & 7) << 2;
            int nl0 = t >> 3;
#pragma unroll
            for (int i = 0; i < 8; ++i) {
                int nl = nl0 + (i << 5);
                float4 wv = *(const float4*)(w + (size_t)nl * 4096 + k0 + k4);
                wsm[k4 + 0][nl] = wv.x;
                wsm[k4 + 1][nl] = wv.y;
                wsm[k4 + 2][nl] = wv.z;
                wsm[k4 + 3][nl] = wv.w;
            }
        }
        __syncthreads();
#pragma unroll
        for (int k = 0; k < 32; ++k) {
            float xv[4], wv[8];
#pragma unroll
            for (int j = 0; j < 4; ++j) xv[j] = xs[bsub * 4 + j][k];
#pragma unroll
            for (int j = 0; j < 8; ++j) wv[j] = wsm[k][nsub + (j << 5)];
#pragma unroll
            for (int jb = 0; jb < 4; ++jb)
#pragma unroll
                for (int jn = 0; jn < 8; ++jn)
                    acc[jb][jn] = fmaf(xv[jb], wv[jn], acc[jb][jn]);
        }
        __syncthreads();
    }
#pragma unroll
    for (int jb = 0; jb < 4; ++jb) {
        int b = bsub * 4 + jb;
#pragma unroll
        for (int jn = 0; jn < 8; ++jn)
            atomicAdd(dst + (size_t)b * dstride + nsub + (jn << 5), acc[jb][jn]);
    }
}

// grid = 24 tiles * 16 splits
__global__ __launch_bounds__(256) void qkv_gemm(
    const float* __restrict__ x, const float* __restrict__ wq,
    const float* __restrict__ wk, const float* __restrict__ wv,
    float* __restrict__ qb, float* __restrict__ knb, float* __restrict__ vnb)
{
    int split = blockIdx.x & 15;
    int tile  = blockIdx.x >> 4;
    const float* w; float* dst; int dstride;
    if (tile < 16)      { w = wq + (size_t)tile * 256 * 4096;        dst = qb  + tile * 256;        dstride = 4096; }
    else if (tile < 20) { w = wk + (size_t)(tile - 16) * 256 * 4096; dst = knb + (tile - 16) * 256; dstride = 1024; }
    else                { w = wv + (size_t)(tile - 20) * 256 * 4096; dst = vnb + (tile - 20) * 256; dstride = 1024; }
    gemm_body(x, w, dst, dstride, split * 256, 256);
}

// grid = 16 tiles * 16 splits
__global__ __launch_bounds__(256) void wo_gemm(
    const float* __restrict__ attn, const float* __restrict__ wo,
    float* __restrict__ out)
{
    int split = blockIdx.x & 15;
    int tile  = blockIdx.x >> 4;
    gemm_body(attn, wo + (size_t)tile * 256 * 4096, out + tile * 256, 4096, split * 256, 256);
}

// ---------------------------------------------------------------------------
// RoPE in-place on q (32 heads) and k_new (8 heads). grid = 32*40, block = 64.
// ---------------------------------------------------------------------------
__global__ void rope_kernel(float* __restrict__ qb, float* __restrict__ knb,
                            const int* __restrict__ lens)
{
    int bid = blockIdx.x;
    int b = bid / 40, r = bid % 40;
    float* row = (r < 32) ? (qb + (size_t)b * 4096 + r * 128)
                          : (knb + (size_t)b * 1024 + (r - 32) * 128);
    int d = threadIdx.x;
    float pos = (float)(lens[b] - 1);
    float inv = exp2f(-(float)d * 0.207620505930460f);  // 10000^(-d/64)
    float fr = pos * inv;
    float s, c;
    sincosf(fr, &s, &c);
    float x1 = row[d], x2 = row[d + 64];
    row[d]      = x1 * c - x2 * s;
    row[d + 64] = x2 * c + x1 * s;
}

// ---------------------------------------------------------------------------
// Flash-decode attention v2: ONE WAVE per (b, kv-head, 256-chunk). Zero
// barriers, zero K/V LDS. Lane = (g = lane>>4 position-in-round, i = lane&15
// dim-slice of 8). Per round (4 positions): K/V rows global->named regs
// (contiguous 512B per 16-lane group), partial dots for ALL 4 GQA heads per
// lane, shfl_xor reductions, wave-uniform online softmax with skip-rescale
// (T13), PV into 32 per-lane accumulators. 1-round named-reg prefetch,
// parity-unrolled (rule #20: every reg access static). The old 4-wave
// barrier-synced design plateaued at ~115us (R4=R7=R8): its 2 barriers +
// 2 LDS round-trips per tile with ~2 blocks/CU were the structural floor.
// ---------------------------------------------------------------------------
#define MUL4(V, S) { V.x *= S; V.y *= S; V.z *= S; V.w *= S; }
#define FMA4(O, P, V) { O.x = fmaf(P, V.x, O.x); O.y = fmaf(P, V.y, O.y); \
                        O.z = fmaf(P, V.z, O.z); O.w = fmaf(P, V.w, O.w); }
#define DOT8(S, QA, QB, K0, K1) { \
    S = fmaf(QA.x, K0.x, S); S = fmaf(QA.y, K0.y, S); \
    S = fmaf(QA.z, K0.z, S); S = fmaf(QA.w, K0.w, S); \
    S = fmaf(QB.x, K1.x, S); S = fmaf(QB.y, K1.y, S); \
    S = fmaf(QB.z, K1.z, S); S = fmaf(QB.w, K1.w, S); }
#define RED16(X) { X += __shfl_xor(X, 1, 64); X += __shfl_xor(X, 2, 64); \
                   X += __shfl_xor(X, 4, 64); X += __shfl_xor(X, 8, 64); }
#define REDG_SUM(X) { X += __shfl_xor(X, 16, 64); X += __shfl_xor(X, 32, 64); }
#define REDG_MAX(X) { X = fmaxf(X, __shfl_xor(X, 16, 64)); \
                      X = fmaxf(X, __shfl_xor(X, 32, 64)); }
#define REDG_SUM4(V) { REDG_SUM(V.x) REDG_SUM(V.y) REDG_SUM(V.z) REDG_SUM(V.w) }

// load round r_'s K/V slice for this lane into named-reg set S (a or b)
#define ALOADR(S, r_) { \
    int sl = ss[((r_) << 2) + g]; \
    const float* kp; const float* vp; \
    if (sl < 0) { kp = knew; vp = vnew; } \
    else { kp = kc + (size_t)sl * 1024 + hoff; vp = vc + (size_t)sl * 1024 + hoff; } \
    S##k0 = *(const float4*)(kp + isl); S##k1 = *(const float4*)(kp + isl + 4); \
    S##v0 = *(const float4*)(vp + isl); S##v1 = *(const float4*)(vp + isl + 4); }

#define ACOMP(S, r_) { \
    float s0 = 0.f, s1 = 0.f, s2 = 0.f, s3 = 0.f; \
    DOT8(s0, q0a, q0b, S##k0, S##k1) \
    DOT8(s1, q1a, q1b, S##k0, S##k1) \
    DOT8(s2, q2a, q2b, S##k0, S##k1) \
    DOT8(s3, q3a, q3b, S##k0, S##k1) \
    RED16(s0) RED16(s1) RED16(s2) RED16(s3) \
    if (((r_) << 2) + g >= pend) { s0 = s1 = s2 = s3 = -INFINITY; } \
    float r0 = s0, r1 = s1, r2 = s2, r3 = s3; \
    REDG_MAX(r0) REDG_MAX(r1) REDG_MAX(r2) REDG_MAX(r3) \
    if (r0 > m0 || r1 > m1 || r2 > m2 || r3 > m3) { \
        float n0 = fmaxf(m0, r0), n1 = fmaxf(m1, r1); \
        float n2 = fmaxf(m2, r2), n3 = fmaxf(m3, r3); \
        float c0 = __expf(m0 - n0), c1 = __expf(m1 - n1); \
        float c2 = __expf(m2 - n2), c3 = __expf(m3 - n3); \
        l0 *= c0; l1 *= c1; l2 *= c2; l3 *= c3; \
        MUL4(o0a, c0) MUL4(o0b, c0) MUL4(o1a, c1) MUL4(o1b, c1) \
        MUL4(o2a, c2) MUL4(o2b, c2) MUL4(o3a, c3) MUL4(o3b, c3) \
        m0 = n0; m1 = n1; m2 = n2; m3 = n3; \
    } \
    float pe0 = __expf(s0 - m0), pe1 = __expf(s1 - m1); \
    float pe2 = __expf(s2 - m2), pe3 = __expf(s3 - m3); \
    float t0 = pe0, t1 = pe1, t2 = pe2, t3 = pe3; \
    REDG_SUM(t0) REDG_SUM(t1) REDG_SUM(t2) REDG_SUM(t3) \
    l0 += t0; l1 += t1; l2 += t2; l3 += t3; \
    FMA4(o0a, pe0, S##v0) FMA4(o0b, pe0, S##v1) \
    FMA4(o1a, pe1, S##v0) FMA4(o1b, pe1, S##v1) \
    FMA4(o2a, pe2, S##v0) FMA4(o2b, pe2, S##v1) \
    FMA4(o3a, pe3, S##v0) FMA4(o3b, pe3, S##v1) }

__global__ __launch_bounds__(64, 1) void attn_kernel(
    const float* __restrict__ kc, const float* __restrict__ vc,
    const float* __restrict__ qb, const float* __restrict__ knb,
    const float* __restrict__ vnb,
    const int* __restrict__ btab, const int* __restrict__ lens,
    float* __restrict__ part)
{
    int bid = blockIdx.x;
    int c = bid & 7, h = (bid >> 3) & 7, b = bid >> 6;
    int len = lens[b];
    int p0 = c << 8;
    if (p0 >= len) return;
    int pend = min(len - p0, 256);
    int nr = (pend + 3) >> 2;     // rounds of 4 positions
    int last = len - 1;

    __shared__ int ss[256];       // slot table; -1 => new k/v row (wave-private)

    int lane = threadIdx.x;
    int g = lane >> 4;            // position-in-round 0..3
    int isl = (lane & 15) << 3;   // dim slice base 0,8,...,120
    int hoff = h * 128;

    {   // slot table: each lane fills 4 consecutive entries (same btab word)
        int idx = lane << 2;
        int p = p0 + idx;
        int bt = btab[b * 128 + (p >> 4)];
        int base = bt * 16 + (p & 15);
        ss[idx]     = (p     == last) ? -1 : base;
        ss[idx + 1] = (p + 1 == last) ? -1 : base + 1;
        ss[idx + 2] = (p + 2 == last) ? -1 : base + 2;
        ss[idx + 3] = (p + 3 == last) ? -1 : base + 3;
    }

    const float* knew = knb + ((size_t)b * 8 + h) * 128;
    const float* vnew = vnb + ((size_t)b * 8 + h) * 128;

    // q for the 4 GQA heads of this kv-head, this lane's 8-dim slice; prescaled
    const float scale = 0.08838834764831845f;   // 1/sqrt(128)
    const float* qrow = qb + (size_t)b * 4096 + (size_t)h * 512;
    float4 q0a = *(const float4*)(qrow + isl),       q0b = *(const float4*)(qrow + isl + 4);
    float4 q1a = *(const float4*)(qrow + 128 + isl), q1b = *(const float4*)(qrow + 128 + isl + 4);
    float4 q2a = *(const float4*)(qrow + 256 + isl), q2b = *(const float4*)(qrow + 256 + isl + 4);
    float4 q3a = *(const float4*)(qrow + 384 + isl), q3b = *(const float4*)(qrow + 384 + isl + 4);
    MUL4(q0a, scale) MUL4(q0b, scale) MUL4(q1a, scale) MUL4(q1b, scale)
    MUL4(q2a, scale) MUL4(q2b, scale) MUL4(q3a, scale) MUL4(q3b, scale)

    float m0 = -INFINITY, m1 = -INFINITY, m2 = -INFINITY, m3 = -INFINITY;
    float l0 = 0.f, l1 = 0.f, l2 = 0.f, l3 = 0.f;
    float4 o0a = {0,0,0,0}, o0b = {0,0,0,0}, o1a = {0,0,0,0}, o1b = {0,0,0,0};
    float4 o2a = {0,0,0,0}, o2b = {0,0,0,0}, o3a = {0,0,0,0}, o3b = {0,0,0,0};

    float4 ak0, ak1, av0, av1, bk0, bk1, bv0, bv1;
    ALOADR(a, 0)
    for (int r = 0; r < nr; r += 2) {
        if (r + 1 < nr) ALOADR(b, r + 1)
        ACOMP(a, r)
        if (r + 1 >= nr) break;
        if (r + 2 < nr) ALOADR(a, r + 2)
        ACOMP(b, r + 1)
    }

    // cross-group O reduction (sum over the 4 position subgroups)
    REDG_SUM4(o0a) REDG_SUM4(o0b) REDG_SUM4(o1a) REDG_SUM4(o1b)
    REDG_SUM4(o2a) REDG_SUM4(o2b) REDG_SUM4(o3a) REDG_SUM4(o3b)

    // partial layout: per (b,h,c): 4 groups x 132 floats [O[128], m, l, pad2]
    float* pgb = part + (size_t)(((b * 8 + h) * 8 + c) * 4) * 132;
    if (lane < 16) {
        *(float4*)(pgb +       isl) = o0a; *(float4*)(pgb +       isl + 4) = o0b;
        *(float4*)(pgb + 132 + isl) = o1a; *(float4*)(pgb + 132 + isl + 4) = o1b;
        *(float4*)(pgb + 264 + isl) = o2a; *(float4*)(pgb + 264 + isl + 4) = o2b;
        *(float4*)(pgb + 396 + isl) = o3a; *(float4*)(pgb + 396 + isl + 4) = o3b;
    }
    if (lane == 0) {
        pgb[128] = m0; pgb[129] = l0;
        pgb[260] = m1; pgb[261] = l1;
        pgb[392] = m2; pgb[393] = l2;
        pgb[524] = m3; pgb[525] = l3;
    }
}

// grid = 256 (b*8+h), block = 256 (4 groups x 64 lanes)
__global__ __launch_bounds__(256) void combine_kernel(
    const float* __restrict__ part, const int* __restrict__ lens,
    float* __restrict__ attn)
{
    int b = blockIdx.x >> 3, h = blockIdx.x & 7;
    int t = threadIdx.x;
    int g = t >> 6, lane = t & 63;
    int len = lens[b];
    int nch = (len + 255) >> 8;
    const float* base = part + (size_t)(b * 8 + h) * 4224 + (size_t)g * 132;
    float M = -INFINITY;
    for (int cc = 0; cc < nch; ++cc)
        M = fmaxf(M, base[(size_t)cc * 528 + 128]);
    float denom = 0.f, a0 = 0.f, a1 = 0.f;
    int d0 = lane << 1;
    for (int cc = 0; cc < nch; ++cc) {
        const float* pg = base + (size_t)cc * 528;
        float w = __expf(pg[128] - M);
        denom += w * pg[129];
        a0 += w * pg[d0];
        a1 += w * pg[d0 + 1];
    }
    float inv = 1.f / denom;
    float* dst = attn + (size_t)b * 4096 + (size_t)(h * 4 + g) * 128 + d0;
    dst[0] = a0 * inv;
    dst[1] = a1 * inv;
}

// ---------------------------------------------------------------------------
// Workspace (floats): qb[32][4096] @0, knb[32*1024] @131072, vnb @163840,
// attn[32][4096] @196608, part[32*8*8*4*132] @327680  (~5.6 MB)
// ---------------------------------------------------------------------------
extern "C" void kernel_launch(void* const* d_in, const int* in_sizes, int n_in,
                              void* d_out, int out_size, void* d_ws, size_t ws_size,
                              hipStream_t stream)
{
    const float* x   = (const float*)d_in[0];
    const float* wq  = (const float*)d_in[1];
    const float* wk  = (const float*)d_in[2];
    const float* wv  = (const float*)d_in[3];
    const float* wo  = (const float*)d_in[4];
    const float* kc  = (const float*)d_in[5];
    const float* vc  = (const float*)d_in[6];
    const int* btab  = (const int*)d_in[8];
    const int* lens  = (const int*)d_in[10];

    float* qb   = (float*)d_ws;
    float* knb  = qb  + 32 * 4096;
    float* vnb  = knb + 32 * 1024;
    float* attn = vnb + 32 * 1024;
    float* part = attn + 32 * 4096;
    float* outp = (float*)d_out;

    hipMemsetAsync(d_ws, 0, (size_t)(32 * 4096 + 2 * 32 * 1024) * sizeof(float), stream);
    hipMemsetAsync(d_out, 0, (size_t)32 * 4096 * sizeof(float), stream);

    qkv_gemm<<<24 * 16, 256, 0, stream>>>(x, wq, wk, wv, qb, knb, vnb);
    rope_kernel<<<32 * 40, 64, 0, stream>>>(qb, knb, lens);
    attn_kernel<<<2048, 64, 0, stream>>>(kc, vc, qb, knb, vnb, btab, lens, part);
    combine_kernel<<<256, 256, 0, stream>>>(part, lens, attn);
    wo_gemm<<<16 * 16, 256, 0, stream>>>(attn, wo, outp);
}

// Round 10
// 178.131 us; speedup vs baseline: 1.1088x; 1.0039x over previous
//
#include <hip/hip_runtime.h>
#include <math.h>

// B=32, HID=4096, NH=32, NKV=8, HS=128, BS=16, MAXS=2048, groups=4

// ---------------------------------------------------------------------------
// Split-K f32 GEMM v1 (known-good). out[b][n] += x[b][:] . w[n][:].
// BM=32, BN=256, BK=32. 256 threads, 32 accumulators/thread.
// ---------------------------------------------------------------------------
__device__ __forceinline__ void gemm_body(
    const float* __restrict__ x, const float* __restrict__ w,
    float* __restrict__ dst, int dstride, int kbase, int kcnt)
{
    __shared__ float xs[32][36];
    __shared__ float wsm[32][257];   // [k][n]
    int t = threadIdx.x;
    float acc[4][8];
#pragma unroll
    for (int i = 0; i < 4; ++i)
#pragma unroll
        for (int j = 0; j < 8; ++j) acc[i][j] = 0.f;

    int nsub = t & 31, bsub = t >> 5;

    for (int kt = 0; kt < kcnt; kt += 32) {
        int k0 = kbase + kt;
        {
            int b = t >> 3, k4 = (t & 7) << 2;
            float4 xv = *(const float4*)(x + (size_t)b * 4096 + k0 + k4);
            *(float4*)&xs[b][k4] = xv;
        }
        {
            int k4 = (t & 7) << 2;
            int nl0 = t >> 3;
#pragma unroll
            for (int i = 0; i < 8; ++i) {
                int nl = nl0 + (i << 5);
                float4 wv = *(const float4*)(w + (size_t)nl * 4096 + k0 + k4);
                wsm[k4 + 0][nl] = wv.x;
                wsm[k4 + 1][nl] = wv.y;
                wsm[k4 + 2][nl] = wv.z;
                wsm[k4 + 3][nl] = wv.w;
            }
        }
        __syncthreads();
#pragma unroll
        for (int k = 0; k < 32; ++k) {
            float xv[4], wv[8];
#pragma unroll
            for (int j = 0; j < 4; ++j) xv[j] = xs[bsub * 4 + j][k];
#pragma unroll
            for (int j = 0; j < 8; ++j) wv[j] = wsm[k][nsub + (j << 5)];
#pragma unroll
            for (int jb = 0; jb < 4; ++jb)
#pragma unroll
                for (int jn = 0; jn < 8; ++jn)
                    acc[jb][jn] = fmaf(xv[jb], wv[jn], acc[jb][jn]);
        }
        __syncthreads();
    }
#pragma unroll
    for (int jb = 0; jb < 4; ++jb) {
        int b = bsub * 4 + jb;
#pragma unroll
        for (int jn = 0; jn < 8; ++jn)
            atomicAdd(dst + (size_t)b * dstride + nsub + (jn << 5), acc[jb][jn]);
    }
}

// grid = 24 tiles * 16 splits
__global__ __launch_bounds__(256) void qkv_gemm(
    const float* __restrict__ x, const float* __restrict__ wq,
    const float* __restrict__ wk, const float* __restrict__ wv,
    float* __restrict__ qb, float* __restrict__ knb, float* __restrict__ vnb)
{
    int split = blockIdx.x & 15;
    int tile  = blockIdx.x >> 4;
    const float* w; float* dst; int dstride;
    if (tile < 16)      { w = wq + (size_t)tile * 256 * 4096;        dst = qb  + tile * 256;        dstride = 4096; }
    else if (tile < 20) { w = wk + (size_t)(tile - 16) * 256 * 4096; dst = knb + (tile - 16) * 256; dstride = 1024; }
    else                { w = wv + (size_t)(tile - 20) * 256 * 4096; dst = vnb + (tile - 20) * 256; dstride = 1024; }
    gemm_body(x, w, dst, dstride, split * 256, 256);
}

// grid = 16 tiles * 16 splits
__global__ __launch_bounds__(256) void wo_gemm(
    const float* __restrict__ attn, const float* __restrict__ wo,
    float* __restrict__ out)
{
    int split = blockIdx.x & 15;
    int tile  = blockIdx.x >> 4;
    gemm_body(attn, wo + (size_t)tile * 256 * 4096, out + tile * 256, 4096, split * 256, 256);
}

// ---------------------------------------------------------------------------
// RoPE in-place on q (32 heads) and k_new (8 heads). grid = 32*40, block = 64.
// ---------------------------------------------------------------------------
__global__ void rope_kernel(float* __restrict__ qb, float* __restrict__ knb,
                            const int* __restrict__ lens)
{
    int bid = blockIdx.x;
    int b = bid / 40, r = bid % 40;
    float* row = (r < 32) ? (qb + (size_t)b * 4096 + r * 128)
                          : (knb + (size_t)b * 1024 + (r - 32) * 128);
    int d = threadIdx.x;
    float pos = (float)(lens[b] - 1);
    float inv = exp2f(-(float)d * 0.207620505930460f);  // 10000^(-d/64)
    float fr = pos * inv;
    float s, c;
    sincosf(fr, &s, &c);
    float x1 = row[d], x2 = row[d + 64];
    row[d]      = x1 * c - x2 * s;
    row[d + 64] = x2 * c + x1 * s;
}

// ---------------------------------------------------------------------------
// Flash-decode attention v3: one wave per (b, kv-head, 128-chunk).
// vs v2 (R9): (1) SUBGROUP-LOCAL online softmax -- each 16-lane group keeps
// its own (m,l,O) per head over its positions; the 4 subgroups merge ONCE at
// the end. Per round only RED16 (16 shfl) remains; no cross-group max/sum, no
// wave-wide branch. (2) chunk 128 -> ~8.5 active waves/CU (2/SIMD).
// (3) 3-deep named-reg K/V prefetch (sets a/b/c, unroll-3): ~2 compute-rounds
// of load cover. All regs named scalars (rule #20).
// ---------------------------------------------------------------------------
#define MUL4(V, S) { V.x *= S; V.y *= S; V.z *= S; V.w *= S; }
#define FMA4(O, P, V) { O.x = fmaf(P, V.x, O.x); O.y = fmaf(P, V.y, O.y); \
                        O.z = fmaf(P, V.z, O.z); O.w = fmaf(P, V.w, O.w); }
#define DOT8(S, QA, QB, K0, K1) { \
    S = fmaf(QA.x, K0.x, S); S = fmaf(QA.y, K0.y, S); \
    S = fmaf(QA.z, K0.z, S); S = fmaf(QA.w, K0.w, S); \
    S = fmaf(QB.x, K1.x, S); S = fmaf(QB.y, K1.y, S); \
    S = fmaf(QB.z, K1.z, S); S = fmaf(QB.w, K1.w, S); }
#define RED16(X) { X += __shfl_xor(X, 1, 64); X += __shfl_xor(X, 2, 64); \
                   X += __shfl_xor(X, 4, 64); X += __shfl_xor(X, 8, 64); }
#define REDG_SUM(X) { X += __shfl_xor(X, 16, 64); X += __shfl_xor(X, 32, 64); }
#define REDG_MAX(X) { X = fmaxf(X, __shfl_xor(X, 16, 64)); \
                      X = fmaxf(X, __shfl_xor(X, 32, 64)); }
#define REDG_SUM4(V) { REDG_SUM(V.x) REDG_SUM(V.y) REDG_SUM(V.z) REDG_SUM(V.w) }

// load round r_'s K/V slice for this lane into named-reg set S
#define ALOADR(S, r_) { \
    int sl = ss[((r_) << 2) + g]; \
    const float* kp; const float* vp; \
    if (sl < 0) { kp = knew; vp = vnew; } \
    else { kp = kc + (size_t)sl * 1024 + hoff; vp = vc + (size_t)sl * 1024 + hoff; } \
    S##k0 = *(const float4*)(kp + isl); S##k1 = *(const float4*)(kp + isl + 4); \
    S##v0 = *(const float4*)(vp + isl); S##v1 = *(const float4*)(vp + isl + 4); }

// per-head subgroup-local online update
#define OUPD(s_, m_, l_, Oa_, Ob_, V0_, V1_, vld_) { \
    if (s_ > m_) { \
        float c_ = __expf(m_ - s_); \
        l_ *= c_; MUL4(Oa_, c_) MUL4(Ob_, c_) \
        m_ = s_; \
    } \
    float pe_ = vld_ ? __expf(s_ - m_) : 0.f; \
    l_ += pe_; \
    FMA4(Oa_, pe_, V0_) FMA4(Ob_, pe_, V1_) }

#define ACOMP(S, r_) { \
    float s0 = 0.f, s1 = 0.f, s2 = 0.f, s3 = 0.f; \
    DOT8(s0, q0a, q0b, S##k0, S##k1) \
    DOT8(s1, q1a, q1b, S##k0, S##k1) \
    DOT8(s2, q2a, q2b, S##k0, S##k1) \
    DOT8(s3, q3a, q3b, S##k0, S##k1) \
    RED16(s0) RED16(s1) RED16(s2) RED16(s3) \
    int vld = (((r_) << 2) + g) < pend; \
    if (!vld) { s0 = s1 = s2 = s3 = -INFINITY; } \
    OUPD(s0, m0, l0, o0a, o0b, S##v0, S##v1, vld) \
    OUPD(s1, m1, l1, o1a, o1b, S##v0, S##v1, vld) \
    OUPD(s2, m2, l2, o2a, o2b, S##v0, S##v1, vld) \
    OUPD(s3, m3, l3, o3a, o3b, S##v0, S##v1, vld) }

__global__ __launch_bounds__(64, 1) void attn_kernel(
    const float* __restrict__ kc, const float* __restrict__ vc,
    const float* __restrict__ qb, const float* __restrict__ knb,
    const float* __restrict__ vnb,
    const int* __restrict__ btab, const int* __restrict__ lens,
    float* __restrict__ part)
{
    int bid = blockIdx.x;
    int c = bid & 15, h = (bid >> 4) & 7, b = bid >> 7;
    int len = lens[b];
    int p0 = c << 7;
    if (p0 >= len) return;
    int pend = min(len - p0, 128);
    int nr = (pend + 3) >> 2;     // rounds of 4 positions
    int last = len - 1;

    __shared__ int ss[128];       // slot table; -1 => new k/v row (wave-private)

    int lane = threadIdx.x;
    int g = lane >> 4;            // position-in-round 0..3
    int isl = (lane & 15) << 3;   // dim slice base 0,8,...,120
    int hoff = h * 128;

    {   // slot table: each lane fills 2 consecutive entries (same btab word)
        int idx = lane << 1;
        int p = p0 + idx;
        int bt = btab[b * 128 + (p >> 4)];
        int base = bt * 16 + (p & 15);
        ss[idx]     = (p     == last) ? -1 : base;
        ss[idx + 1] = (p + 1 == last) ? -1 : base + 1;
    }

    const float* knew = knb + ((size_t)b * 8 + h) * 128;
    const float* vnew = vnb + ((size_t)b * 8 + h) * 128;

    // q for the 4 GQA heads of this kv-head, this lane's 8-dim slice; prescaled
    const float scale = 0.08838834764831845f;   // 1/sqrt(128)
    const float* qrow = qb + (size_t)b * 4096 + (size_t)h * 512;
    float4 q0a = *(const float4*)(qrow + isl),       q0b = *(const float4*)(qrow + isl + 4);
    float4 q1a = *(const float4*)(qrow + 128 + isl), q1b = *(const float4*)(qrow + 128 + isl + 4);
    float4 q2a = *(const float4*)(qrow + 256 + isl), q2b = *(const float4*)(qrow + 256 + isl + 4);
    float4 q3a = *(const float4*)(qrow + 384 + isl), q3b = *(const float4*)(qrow + 384 + isl + 4);
    MUL4(q0a, scale) MUL4(q0b, scale) MUL4(q1a, scale) MUL4(q1b, scale)
    MUL4(q2a, scale) MUL4(q2b, scale) MUL4(q3a, scale) MUL4(q3b, scale)

    float m0 = -INFINITY, m1 = -INFINITY, m2 = -INFINITY, m3 = -INFINITY;
    float l0 = 0.f, l1 = 0.f, l2 = 0.f, l3 = 0.f;
    float4 o0a = {0,0,0,0}, o0b = {0,0,0,0}, o1a = {0,0,0,0}, o1b = {0,0,0,0};
    float4 o2a = {0,0,0,0}, o2b = {0,0,0,0}, o3a = {0,0,0,0}, o3b = {0,0,0,0};

    float4 ak0, ak1, av0, av1;
    float4 bk0, bk1, bv0, bv1;
    float4 ck0, ck1, cv0, cv1;
    ALOADR(a, 0)
    if (1 < nr) ALOADR(b, 1)
    if (2 < nr) ALOADR(c, 2)
    for (int r = 0; r < nr; r += 3) {
        ACOMP(a, r)
        if (r + 3 < nr) ALOADR(a, r + 3)
        if (r + 1 >= nr) break;
        ACOMP(b, r + 1)
        if (r + 4 < nr) ALOADR(b, r + 4)
        if (r + 2 >= nr) break;
        ACOMP(c, r + 2)
        if (r + 5 < nr) ALOADR(c, r + 5)
    }

    // merge the 4 subgroup partial softmaxes (once per wave)
    float M0 = m0, M1 = m1, M2 = m2, M3 = m3;
    REDG_MAX(M0) REDG_MAX(M1) REDG_MAX(M2) REDG_MAX(M3)
    float w0 = __expf(m0 - M0), w1 = __expf(m1 - M1);
    float w2 = __expf(m2 - M2), w3 = __expf(m3 - M3);
    float L0 = w0 * l0, L1 = w1 * l1, L2 = w2 * l2, L3 = w3 * l3;
    REDG_SUM(L0) REDG_SUM(L1) REDG_SUM(L2) REDG_SUM(L3)
    MUL4(o0a, w0) MUL4(o0b, w0) MUL4(o1a, w1) MUL4(o1b, w1)
    MUL4(o2a, w2) MUL4(o2b, w2) MUL4(o3a, w3) MUL4(o3b, w3)
    REDG_SUM4(o0a) REDG_SUM4(o0b) REDG_SUM4(o1a) REDG_SUM4(o1b)
    REDG_SUM4(o2a) REDG_SUM4(o2b) REDG_SUM4(o3a) REDG_SUM4(o3b)

    // partial layout: per (b,h,c): 4 heads x 132 floats [O[128], m, l, pad2]
    float* pgb = part + (size_t)(((b * 8 + h) * 16 + c) * 4) * 132;
    if (lane < 16) {
        *(float4*)(pgb +       isl) = o0a; *(float4*)(pgb +       isl + 4) = o0b;
        *(float4*)(pgb + 132 + isl) = o1a; *(float4*)(pgb + 132 + isl + 4) = o1b;
        *(float4*)(pgb + 264 + isl) = o2a; *(float4*)(pgb + 264 + isl + 4) = o2b;
        *(float4*)(pgb + 396 + isl) = o3a; *(float4*)(pgb + 396 + isl + 4) = o3b;
    }
    if (lane == 0) {
        pgb[128] = M0; pgb[129] = L0;
        pgb[260] = M1; pgb[261] = L1;
        pgb[392] = M2; pgb[393] = L2;
        pgb[524] = M3; pgb[525] = L3;
    }
}

// grid = 256 (b*8+h), block = 256 (4 heads x 64 lanes)
__global__ __launch_bounds__(256) void combine_kernel(
    const float* __restrict__ part, const int* __restrict__ lens,
    float* __restrict__ attn)
{
    int b = blockIdx.x >> 3, h = blockIdx.x & 7;
    int t = threadIdx.x;
    int g = t >> 6, lane = t & 63;
    int len = lens[b];
    int nch = (len + 127) >> 7;
    const float* base = part + (size_t)(b * 8 + h) * 8448 + (size_t)g * 132;
    float M = -INFINITY;
    for (int cc = 0; cc < nch; ++cc)
        M = fmaxf(M, base[(size_t)cc * 528 + 128]);
    float denom = 0.f, a0 = 0.f, a1 = 0.f;
    int d0 = lane << 1;
    for (int cc = 0; cc < nch; ++cc) {
        const float* pg = base + (size_t)cc * 528;
        float w = __expf(pg[128] - M);
        denom += w * pg[129];
        a0 += w * pg[d0];
        a1 += w * pg[d0 + 1];
    }
    float inv = 1.f / denom;
    float* dst = attn + (size_t)b * 4096 + (size_t)(h * 4 + g) * 128 + d0;
    dst[0] = a0 * inv;
    dst[1] = a1 * inv;
}

// ---------------------------------------------------------------------------
// Workspace (floats): qb[32][4096] @0, knb[32*1024] @131072, vnb @163840,
// attn[32][4096] @196608, part[32*8*16*4*132] @327680 (~8.7MB; total ~10MB)
// ---------------------------------------------------------------------------
extern "C" void kernel_launch(void* const* d_in, const int* in_sizes, int n_in,
                              void* d_out, int out_size, void* d_ws, size_t ws_size,
                              hipStream_t stream)
{
    const float* x   = (const float*)d_in[0];
    const float* wq  = (const float*)d_in[1];
    const float* wk  = (const float*)d_in[2];
    const float* wv  = (const float*)d_in[3];
    const float* wo  = (const float*)d_in[4];
    const float* kc  = (const float*)d_in[5];
    const float* vc  = (const float*)d_in[6];
    const int* btab  = (const int*)d_in[8];
    const int* lens  = (const int*)d_in[10];

    float* qb   = (float*)d_ws;
    float* knb  = qb  + 32 * 4096;
    float* vnb  = knb + 32 * 1024;
    float* attn = vnb + 32 * 1024;
    float* part = attn + 32 * 4096;
    float* outp = (float*)d_out;

    hipMemsetAsync(d_ws, 0, (size_t)(32 * 4096 + 2 * 32 * 1024) * sizeof(float), stream);
    hipMemsetAsync(d_out, 0, (size_t)32 * 4096 * sizeof(float), stream);

    qkv_gemm<<<24 * 16, 256, 0, stream>>>(x, wq, wk, wv, qb, knb, vnb);
    rope_kernel<<<32 * 40, 64, 0, stream>>>(qb, knb, lens);
    attn_kernel<<<4096, 64, 0, stream>>>(kc, vc, qb, knb, vnb, btab, lens, part);
    combine_kernel<<<256, 256, 0, stream>>>(part, lens, attn);
    wo_gemm<<<16 * 16, 256, 0, stream>>>(attn, wo, outp);
}